// Round 16
// baseline (12244.792 us; speedup 1.0000x reference)
//
#include <hip/hip_runtime.h>
#include <hip/hip_bf16.h>

#define B_SZ 1024
#define T_SZ 128
#define D_SZ 256
#define H_SZ 512
#define NBLK 256
#define NTHR 512

typedef __attribute__((ext_vector_type(8))) short short8;
typedef __attribute__((ext_vector_type(4))) float f32x4;

__device__ inline f32x4 mfma16(short8 a, short8 b, f32x4 c) {
  return __builtin_amdgcn_mfma_f32_16x16x32_bf16(a, b, c, 0, 0, 0);
}

// plain write-back state store (r13-proven: vmcnt drain + barrier = visible)
__device__ inline void st_bf16(__hip_bfloat16* p, float v) {
  union { __hip_bfloat16 b; unsigned short u; } cv;
  cv.b = __float2bfloat16(v);
  unsigned int vv = cv.u;
  asm volatile("global_store_short %0, %1, off" :: "v"(p), "v"(vv) : "memory");
}

// coherent state load, 16B: two agent-scope relaxed atomic 64-bit loads.
// Bypasses stale L1 (atomics go to L2) AND is compiler-tracked, so the
// scheduler can hoist/pipeline these into the MFMA chain (unlike asm loads).
__device__ __forceinline__ short8 ldA(const __hip_bfloat16* p) {
  const unsigned long long* q = (const unsigned long long*)p;
  unsigned long long lo = __hip_atomic_load(q, __ATOMIC_RELAXED, __HIP_MEMORY_SCOPE_AGENT);
  unsigned long long hi = __hip_atomic_load(q + 1, __ATOMIC_RELAXED, __HIP_MEMORY_SCOPE_AGENT);
  union { unsigned long long u[2]; short8 s; } cv;
  cv.u[0] = lo; cv.u[1] = hi;
  return cv.s;
}

// Strip-local 8-block barrier: monotonic counter, relaxed atomics, no fences.
__device__ __forceinline__ void sbar(unsigned* scnt, unsigned p) {
  asm volatile("s_waitcnt vmcnt(0)" ::: "memory");  // all waves drain stores
  __syncthreads();
  if (threadIdx.x == 0) {
    __hip_atomic_fetch_add(scnt, 1u, __ATOMIC_RELAXED, __HIP_MEMORY_SCOPE_AGENT);
    while (__hip_atomic_load(scnt, __ATOMIC_RELAXED, __HIP_MEMORY_SCOPE_AGENT) < p * 8u)
      __builtin_amdgcn_s_sleep(1);
  }
  __syncthreads();
}

__global__ __launch_bounds__(512, 1) void k_fused(
    const float* __restrict__ xg, const float* __restrict__ xtime,
    const __hip_bfloat16* __restrict__ W1t, const float* __restrict__ b1,
    const __hip_bfloat16* __restrict__ W2t, const float* __restrict__ b2,
    const __hip_bfloat16* __restrict__ Wzrt, const float* __restrict__ bz,
    const float* __restrict__ br, const __hip_bfloat16* __restrict__ Wnt,
    const float* __restrict__ bn, float* __restrict__ hf, float* __restrict__ hstdf,
    __hip_bfloat16* __restrict__ hbf, __hip_bfloat16* __restrict__ Ubf,
    __hip_bfloat16* __restrict__ hodeb, __hip_bfloat16* __restrict__ hstdb,
    __hip_bfloat16* __restrict__ A4, __hip_bfloat16* __restrict__ xstep,
    unsigned* __restrict__ bar) {
  // NO LDS: both MFMA operands load straight to VGPRs; compiler pipelines.
  int tid = threadIdx.x, lane = tid & 63, wv = tid >> 6;
  int lr = lane & 15, lg = lane >> 4;
  int rh = wv >> 2, cq = wv & 3;   // wave role: row-half (0/1), col-quarter
  int b = blockIdx.x;
  // r13 mapping: strips co-located per XCD (4 strips x 8 slices per XCD)
  int xcd = b & 7;
  int j = b >> 3;
  int i = (xcd << 2) | (j >> 3);   // strip 0..31
  int s = j & 7;                   // slice 0..7
  int m0 = i << 5;                 // 32-row strip
  int nA = s << 6;                 // owned 64-column base (ALL phases)
  unsigned* scnt = bar + i * 32;
  unsigned p = 0;
  int cl = (cq << 4) + lr;
  int col = nA + cl;               // owned output column
  int row0 = m0 + (rh << 4) + (lg << 2);
  int arow = m0 + (rh << 4) + lr;  // A-fragment row for this lane
  float hreg[4] = {0.f, 0.f, 0.f, 0.f}, sreg[4] = {0.f, 0.f, 0.f, 0.f};
  float oreg[4], zreg[4];

  // per-wave B pointers (lane-resolved): W^T row = output col; weights are
  // immutable -> plain L1-cached loads
  const __hip_bfloat16* w1p = W1t + (size_t)col * H_SZ + (lg << 3);
  const __hip_bfloat16* w2p = W2t + (size_t)col * H_SZ + (lg << 3);
  const __hip_bfloat16* wzp = Wzrt + (size_t)col * 1280 + (lg << 3);
  const __hip_bfloat16* wrp = Wzrt + (size_t)(512 + col) * 1280 + (lg << 3);
  const __hip_bfloat16* wmp = Wnt + (size_t)col * 1280 + (lg << 3);
  const __hip_bfloat16* wsp = Wnt + (size_t)(512 + col) * 1280 + (lg << 3);

#pragma unroll 1
  for (int t = 0; t < T_SZ; ++t) {
    sbar(scnt, ++p);  // strip's hbf/hstdb of step t-1 visible
    // ======== P1: U = tanh(h @ W1 + b1), owned cols ========
    {
      f32x4 acc = {};
#pragma unroll
      for (int q = 0; q < 16; ++q) {
        short8 a = ldA(hbf + (size_t)arow * H_SZ + (q << 5) + (lg << 3));
        short8 bb = *(const short8*)(w1p + (q << 5));
        acc = mfma16(a, bb, acc);
      }
      float bi = b1[col];
#pragma unroll
      for (int r = 0; r < 4; ++r)
        st_bf16(&Ubf[(size_t)(row0 + r) * H_SZ + col], tanhf(acc[r] + bi));
    }
    sbar(scnt, ++p);
    // ======== P2: h_ode = h + dt*(U @ W2 + b2); x slice -> bf16 ========
    {
      f32x4 acc = {};
#pragma unroll
      for (int q = 0; q < 16; ++q) {
        short8 a = ldA(Ubf + (size_t)arow * H_SZ + (q << 5) + (lg << 3));
        short8 bb = *(const short8*)(w2p + (q << 5));
        acc = mfma16(a, bb, acc);
      }
      float dtv = (t == 0) ? 0.01f : (xtime[t] - xtime[t - 1]);
      float bi = b2[col];
#pragma unroll
      for (int r = 0; r < 4; ++r) {
        float v = hreg[r] + dtv * (acc[r] + bi);
        oreg[r] = v;
        st_bf16(&hodeb[(size_t)(row0 + r) * H_SZ + col], v);
      }
      {  // x[:, t, s-slice] -> bf16 (32 strip rows, 32 cols per slice)
        int colx = (s << 5) + (tid & 31);
#pragma unroll
        for (int it2 = 0; it2 < 2; ++it2) {
          int row = m0 + (tid >> 5) + (it2 << 4);
          float xv = xg[((size_t)row * T_SZ + t) * D_SZ + colx];
          st_bf16(&xstep[(size_t)row * D_SZ + colx], xv);
        }
      }
    }
    sbar(scnt, ++p);
    // ======== P3: z,r = sigmoid(cat @ WzrT), owned cols; build A4 ========
    {
      f32x4 acc0 = {}, acc1 = {};
#pragma unroll
      for (int q = 0; q < 40; ++q) {
        int k = q << 5;
        const __hip_bfloat16* ap;
        if (k < 512)       ap = hodeb + (size_t)arow * H_SZ + k;
        else if (k < 1024) ap = hstdb + (size_t)arow * H_SZ + (k - 512);
        else               ap = xstep + (size_t)arow * D_SZ + (k - 1024);
        short8 a = ldA(ap + (lg << 3));
        short8 b0 = *(const short8*)(wzp + k);
        short8 b1f = *(const short8*)(wrp + k);
        acc0 = mfma16(a, b0, acc0);
        acc1 = mfma16(a, b1f, acc1);
      }
      float bz_ = bz[col], br_ = br[col];
#pragma unroll
      for (int r = 0; r < 4; ++r) {
        int row = row0 + r;
        zreg[r] = 1.f / (1.f + expf(-(acc0[r] + bz_)));
        float g = 1.f / (1.f + expf(-(acc1[r] + br_)));
        st_bf16(&A4[(size_t)row * 1024 + col], oreg[r] * g);
        st_bf16(&A4[(size_t)row * 1024 + 512 + col], sreg[r] * g);
      }
    }
    sbar(scnt, ++p);
    // ======== P4: n_mean,n_std owned cols; GRU update in registers ========
    {
      f32x4 acc0 = {}, acc1 = {};
#pragma unroll
      for (int q = 0; q < 40; ++q) {
        int k = q << 5;
        const __hip_bfloat16* ap;
        if (k < 1024) ap = A4 + (size_t)arow * 1024 + k;
        else          ap = xstep + (size_t)arow * D_SZ + (k - 1024);
        short8 a = ldA(ap + (lg << 3));
        short8 b0 = *(const short8*)(wmp + k);
        short8 b1f = *(const short8*)(wsp + k);
        acc0 = mfma16(a, b0, acc0);
        acc1 = mfma16(a, b1f, acc1);
      }
      float bm = bn[col], bs = bn[512 + col];
#pragma unroll
      for (int r = 0; r < 4; ++r) {
        int row = row0 + r;
        float z = zreg[r];
        float hn = (1.f - z) * (acc0[r] + bm) + z * oreg[r];
        hreg[r] = hn;
        st_bf16(&hbf[(size_t)row * H_SZ + col], hn);
        float ns = fabsf(acc1[r] + bs);
        float sn = fabsf((1.f - z) * ns + z * sreg[r]);
        sreg[r] = sn;
        st_bf16(&hstdb[(size_t)row * H_SZ + col], sn);
      }
    }
  }
  // final output: register state -> global
#pragma unroll
  for (int r = 0; r < 4; ++r) {
    int row = row0 + r;
    hf[(size_t)row * H_SZ + col] = hreg[r];
    hstdf[(size_t)row * H_SZ + col] = sreg[r];
  }
}

// =============== prep: W[k][n] f32  ->  Wt[n][k] bf16 =====================
__global__ void k_wt(const float* __restrict__ W, __hip_bfloat16* __restrict__ Wt,
                     int K, int N, int ld) {
  size_t i = (size_t)blockIdx.x * 256 + threadIdx.x;
  if (i >= (size_t)K * N) return;
  int n = (int)(i / K), k = (int)(i % K);
  Wt[(size_t)n * ld + k] = __float2bfloat16(W[(size_t)k * N + n]);
}

extern "C" void kernel_launch(void* const* d_in, const int* in_sizes, int n_in,
                              void* d_out, int out_size, void* d_ws, size_t ws_size,
                              hipStream_t stream) {
  const float* x     = (const float*)d_in[0];
  const float* xtime = (const float*)d_in[1];
  const float* W1    = (const float*)d_in[2];
  const float* b1    = (const float*)d_in[3];
  const float* W2    = (const float*)d_in[4];
  const float* b2    = (const float*)d_in[5];
  const float* Wz    = (const float*)d_in[6];
  const float* bz    = (const float*)d_in[7];
  const float* Wr    = (const float*)d_in[8];
  const float* br    = (const float*)d_in[9];
  const float* Wn    = (const float*)d_in[10];
  const float* bn    = (const float*)d_in[11];

  char* p = (char*)d_ws;
  __hip_bfloat16* W1t   = (__hip_bfloat16*)(p + 0);
  __hip_bfloat16* W2t   = (__hip_bfloat16*)(p + 524288);
  __hip_bfloat16* Wzrt  = (__hip_bfloat16*)(p + 1048576);
  __hip_bfloat16* Wnt   = (__hip_bfloat16*)(p + 3670016);
  float*          hf    = (float*)(p + 6291456);
  float*          hstdf = (float*)(p + 8388608);
  __hip_bfloat16* hbf   = (__hip_bfloat16*)(p + 14680064);
  __hip_bfloat16* Ubf   = (__hip_bfloat16*)(p + 15728640);
  __hip_bfloat16* hodeb = (__hip_bfloat16*)(p + 16777216);
  __hip_bfloat16* hstdb = (__hip_bfloat16*)(p + 17825792);
  __hip_bfloat16* A4    = (__hip_bfloat16*)(p + 18874368);
  __hip_bfloat16* xstep = (__hip_bfloat16*)(p + 20971520);
  unsigned*       bar   = (unsigned*)(p + 21495808);

  hipMemsetAsync(hbf, 0, 1048576, stream);
  hipMemsetAsync(hstdb, 0, 1048576, stream);
  hipMemsetAsync(bar, 0, 8192, stream);

  k_wt<<<(512 * 512 + 255) / 256, 256, 0, stream>>>(W1, W1t, 512, 512, 512);
  k_wt<<<(512 * 512 + 255) / 256, 256, 0, stream>>>(W2, W2t, 512, 512, 512);
  k_wt<<<(1280 * 512 + 255) / 256, 256, 0, stream>>>(Wz, Wzrt, 1280, 512, 1280);
  k_wt<<<(1280 * 512 + 255) / 256, 256, 0, stream>>>(Wr, Wzrt + (size_t)512 * 1280, 1280, 512, 1280);
  k_wt<<<(1280 * 1024 + 255) / 256, 256, 0, stream>>>(Wn, Wnt, 1280, 1024, 1280);

  // persistent kernel: r13 mapping; ZERO LDS — A via agent-scope atomic
  // 16B loads (L1-bypass, compiler-pipelined), B via plain cached loads;
  // free-running unrolled k-loops; 4 strip barriers per step
  k_fused<<<NBLK, NTHR, 0, stream>>>(x, xtime, W1t, b1, W2t, b2, Wzrt, bz, br,
                                     Wnt, bn, hf, hstdf, hbf, Ubf,
                                     hodeb, hstdb, A4, xstep, bar);

  hipMemcpyAsync(d_out, hf, 2097152, hipMemcpyDeviceToDevice, stream);
  hipMemcpyAsync((char*)d_out + 2097152, hstdf, 2097152, hipMemcpyDeviceToDevice, stream);
}

// Round 18
// 9164.621 us; speedup vs baseline: 1.3361x; 1.3361x over previous
//
#include <hip/hip_runtime.h>
#include <hip/hip_bf16.h>

#define B_SZ 1024
#define T_SZ 128
#define D_SZ 256
#define H_SZ 512
#define NBLK 256
#define NTHR 512

typedef __attribute__((ext_vector_type(8))) short short8;
typedef __attribute__((ext_vector_type(4))) float f32x4;
typedef __attribute__((ext_vector_type(4))) unsigned int uint4v;

__device__ inline f32x4 mfma16(short8 a, short8 b, f32x4 c) {
  return __builtin_amdgcn_mfma_f32_16x16x32_bf16(a, b, c, 0, 0, 0);
}

// plain write-back state store (r13-proven: vmcnt drain + barrier = visible
// to same-XCD sc0 readers)
__device__ inline void st_bf16(__hip_bfloat16* p, float v) {
  union { __hip_bfloat16 b; unsigned short u; } cv;
  cv.b = __float2bfloat16(v);
  unsigned int vv = cv.u;
  asm volatile("global_store_short %0, %1, off" :: "v"(p), "v"(vv) : "memory");
}

#if __has_builtin(__builtin_amdgcn_make_buffer_rsrc) && __has_builtin(__builtin_amdgcn_raw_buffer_load_b128)
#define USE_BUF 1
// coherent 16B state load: buffer_load_dwordx4 sc0 (L1-bypass, L2-fresh).
// A real load intrinsic -> compiler batches/pipelines it into the MFMA chain.
__device__ __forceinline__ __amdgpu_buffer_rsrc_t make_rs(const void* p) {
  return __builtin_amdgcn_make_buffer_rsrc(const_cast<void*>(p), (short)0,
                                           (int)0xFFFFFFFF, 0x00020000);
}
__device__ __forceinline__ short8 ldA(__amdgpu_buffer_rsrc_t rs, int byteOff) {
  uint4v v = __builtin_amdgcn_raw_buffer_load_b128(rs, byteOff, 0, 1 /*sc0*/);
  union { uint4v u; short8 s; } cv; cv.u = v; return cv.s;
}
typedef __amdgpu_buffer_rsrc_t rsrc_t;
#else
#define USE_BUF 0
// fallback: sc0 global load via inline asm (correct, less pipelinable)
typedef const __hip_bfloat16* rsrc_t;
__device__ __forceinline__ rsrc_t make_rs(const void* p) { return (rsrc_t)p; }
__device__ __forceinline__ short8 ldA(rsrc_t base, int byteOff) {
  uint4v v;
  const char* addr = (const char*)base + byteOff;
  asm volatile("global_load_dwordx4 %0, %1, off sc0" : "=v"(v) : "v"(addr) : "memory");
  union { uint4v u; short8 s; } cv; cv.u = v; return cv.s;
}
#endif

// Strip-local 8-block barrier: monotonic counter, relaxed atomics, no fences.
__device__ __forceinline__ void sbar(unsigned* scnt, unsigned p) {
  asm volatile("s_waitcnt vmcnt(0)" ::: "memory");  // all waves drain stores
  __syncthreads();
  if (threadIdx.x == 0) {
    __hip_atomic_fetch_add(scnt, 1u, __ATOMIC_RELAXED, __HIP_MEMORY_SCOPE_AGENT);
    while (__hip_atomic_load(scnt, __ATOMIC_RELAXED, __HIP_MEMORY_SCOPE_AGENT) < p * 8u)
      __builtin_amdgcn_s_sleep(1);
  }
  __syncthreads();
}

__global__ __launch_bounds__(512, 1) void k_fused(
    const float* __restrict__ xg, const float* __restrict__ xtime,
    const __hip_bfloat16* __restrict__ W1t, const float* __restrict__ b1,
    const __hip_bfloat16* __restrict__ W2t, const float* __restrict__ b2,
    const __hip_bfloat16* __restrict__ Wzrt, const float* __restrict__ bz,
    const float* __restrict__ br, const __hip_bfloat16* __restrict__ Wnt,
    const float* __restrict__ bn, float* __restrict__ hf, float* __restrict__ hstdf,
    __hip_bfloat16* __restrict__ hbf, __hip_bfloat16* __restrict__ Ubf,
    __hip_bfloat16* __restrict__ hodeb, __hip_bfloat16* __restrict__ hstdb,
    __hip_bfloat16* __restrict__ A4, __hip_bfloat16* __restrict__ xstep,
    unsigned* __restrict__ bar) {
  // ZERO LDS: A via sc0 buffer-loads, B via plain cached loads, all to VGPRs.
  int tid = threadIdx.x, lane = tid & 63, wv = tid >> 6;
  int lr = lane & 15, lg = lane >> 4;
  int rh = wv >> 2, cq = wv & 3;   // wave role: row-half (0/1), col-quarter
  int b = blockIdx.x;
  // r13 mapping: strips co-located per XCD (4 strips x 8 slices per XCD)
  int xcd = b & 7;
  int j = b >> 3;
  int i = (xcd << 2) | (j >> 3);   // strip 0..31
  int s = j & 7;                   // slice 0..7
  int m0 = i << 5;                 // 32-row strip
  int nA = s << 6;                 // owned 64-column base (ALL phases)
  unsigned* scnt = bar + i * 32;
  unsigned p = 0;
  int cl = (cq << 4) + lr;
  int col = nA + cl;               // owned output column
  int row0 = m0 + (rh << 4) + (lg << 2);
  int arow = m0 + (rh << 4) + lr;  // A-fragment row for this lane
  float hreg[4] = {0.f, 0.f, 0.f, 0.f}, sreg[4] = {0.f, 0.f, 0.f, 0.f};
  float oreg[4], zreg[4];

  // state-buffer resources (wave-uniform descriptors)
  rsrc_t rsH = make_rs(hbf), rsU = make_rs(Ubf);
  rsrc_t rsO = make_rs(hodeb), rsS = make_rs(hstdb);
  rsrc_t rsA4 = make_rs(A4), rsX = make_rs(xstep);
  // per-thread A base byte-offsets
  int aH = (arow * H_SZ + (lg << 3)) * 2;    // stride-512 bf16 buffers
  int aA4 = (arow * 1024 + (lg << 3)) * 2;   // A4
  int aX = (arow * D_SZ + (lg << 3)) * 2;    // xstep

  // per-wave B pointers (lane-resolved, immutable -> plain L1-cached loads)
  const __hip_bfloat16* w1p = W1t + (size_t)col * H_SZ + (lg << 3);
  const __hip_bfloat16* w2p = W2t + (size_t)col * H_SZ + (lg << 3);
  const __hip_bfloat16* wzp = Wzrt + (size_t)col * 1280 + (lg << 3);
  const __hip_bfloat16* wrp = Wzrt + (size_t)(512 + col) * 1280 + (lg << 3);
  const __hip_bfloat16* wmp = Wnt + (size_t)col * 1280 + (lg << 3);
  const __hip_bfloat16* wsp = Wnt + (size_t)(512 + col) * 1280 + (lg << 3);

#pragma unroll 1
  for (int t = 0; t < T_SZ; ++t) {
    sbar(scnt, ++p);  // strip's hbf/hstdb of step t-1 visible
    // ======== P1: U = tanh(h @ W1 + b1), owned cols ========
    {
      f32x4 acc = {};
#pragma unroll
      for (int q = 0; q < 16; ++q) {
        short8 a = ldA(rsH, aH + (q << 6));
        short8 bb = *(const short8*)(w1p + (q << 5));
        acc = mfma16(a, bb, acc);
      }
      float bi = b1[col];
#pragma unroll
      for (int r = 0; r < 4; ++r)
        st_bf16(&Ubf[(size_t)(row0 + r) * H_SZ + col], tanhf(acc[r] + bi));
    }
    sbar(scnt, ++p);
    // ======== P2: h_ode = h + dt*(U @ W2 + b2); x slice -> bf16 ========
    {
      f32x4 acc = {};
#pragma unroll
      for (int q = 0; q < 16; ++q) {
        short8 a = ldA(rsU, aH + (q << 6));
        short8 bb = *(const short8*)(w2p + (q << 5));
        acc = mfma16(a, bb, acc);
      }
      float dtv = (t == 0) ? 0.01f : (xtime[t] - xtime[t - 1]);
      float bi = b2[col];
#pragma unroll
      for (int r = 0; r < 4; ++r) {
        float v = hreg[r] + dtv * (acc[r] + bi);
        oreg[r] = v;
        st_bf16(&hodeb[(size_t)(row0 + r) * H_SZ + col], v);
      }
      {  // x[:, t, s-slice] -> bf16 (32 strip rows, 32 cols per slice)
        int colx = (s << 5) + (tid & 31);
#pragma unroll
        for (int it2 = 0; it2 < 2; ++it2) {
          int row = m0 + (tid >> 5) + (it2 << 4);
          float xv = xg[((size_t)row * T_SZ + t) * D_SZ + colx];
          st_bf16(&xstep[(size_t)row * D_SZ + colx], xv);
        }
      }
    }
    sbar(scnt, ++p);
    // ======== P3: z,r = sigmoid(cat @ WzrT), owned cols; build A4 ========
    {
      f32x4 acc0 = {}, acc1 = {};
#pragma unroll
      for (int q = 0; q < 40; ++q) {
        int k = q << 5;
        short8 a;
        if (k < 512)       a = ldA(rsO, aH + (k << 1));
        else if (k < 1024) a = ldA(rsS, aH + ((k - 512) << 1));
        else               a = ldA(rsX, aX + ((k - 1024) << 1));
        short8 b0 = *(const short8*)(wzp + k);
        short8 b1f = *(const short8*)(wrp + k);
        acc0 = mfma16(a, b0, acc0);
        acc1 = mfma16(a, b1f, acc1);
      }
      float bz_ = bz[col], br_ = br[col];
#pragma unroll
      for (int r = 0; r < 4; ++r) {
        int row = row0 + r;
        zreg[r] = 1.f / (1.f + expf(-(acc0[r] + bz_)));
        float g = 1.f / (1.f + expf(-(acc1[r] + br_)));
        st_bf16(&A4[(size_t)row * 1024 + col], oreg[r] * g);
        st_bf16(&A4[(size_t)row * 1024 + 512 + col], sreg[r] * g);
      }
    }
    sbar(scnt, ++p);
    // ======== P4: n_mean,n_std owned cols; GRU update in registers ========
    {
      f32x4 acc0 = {}, acc1 = {};
#pragma unroll
      for (int q = 0; q < 40; ++q) {
        int k = q << 5;
        short8 a;
        if (k < 1024) a = ldA(rsA4, aA4 + (k << 1));
        else          a = ldA(rsX, aX + ((k - 1024) << 1));
        short8 b0 = *(const short8*)(wmp + k);
        short8 b1f = *(const short8*)(wsp + k);
        acc0 = mfma16(a, b0, acc0);
        acc1 = mfma16(a, b1f, acc1);
      }
      float bm = bn[col], bs = bn[512 + col];
#pragma unroll
      for (int r = 0; r < 4; ++r) {
        int row = row0 + r;
        float z = zreg[r];
        float hn = (1.f - z) * (acc0[r] + bm) + z * oreg[r];
        hreg[r] = hn;
        st_bf16(&hbf[(size_t)row * H_SZ + col], hn);
        float ns = fabsf(acc1[r] + bs);
        float sn = fabsf((1.f - z) * ns + z * sreg[r]);
        sreg[r] = sn;
        st_bf16(&hstdb[(size_t)row * H_SZ + col], sn);
      }
    }
  }
  // final output: register state -> global
#pragma unroll
  for (int r = 0; r < 4; ++r) {
    int row = row0 + r;
    hf[(size_t)row * H_SZ + col] = hreg[r];
    hstdf[(size_t)row * H_SZ + col] = sreg[r];
  }
}

// =============== prep: W[k][n] f32  ->  Wt[n][k] bf16 =====================
__global__ void k_wt(const float* __restrict__ W, __hip_bfloat16* __restrict__ Wt,
                     int K, int N, int ld) {
  size_t i = (size_t)blockIdx.x * 256 + threadIdx.x;
  if (i >= (size_t)K * N) return;
  int n = (int)(i / K), k = (int)(i % K);
  Wt[(size_t)n * ld + k] = __float2bfloat16(W[(size_t)k * N + n]);
}

extern "C" void kernel_launch(void* const* d_in, const int* in_sizes, int n_in,
                              void* d_out, int out_size, void* d_ws, size_t ws_size,
                              hipStream_t stream) {
  const float* x     = (const float*)d_in[0];
  const float* xtime = (const float*)d_in[1];
  const float* W1    = (const float*)d_in[2];
  const float* b1    = (const float*)d_in[3];
  const float* W2    = (const float*)d_in[4];
  const float* b2    = (const float*)d_in[5];
  const float* Wz    = (const float*)d_in[6];
  const float* bz    = (const float*)d_in[7];
  const float* Wr    = (const float*)d_in[8];
  const float* br    = (const float*)d_in[9];
  const float* Wn    = (const float*)d_in[10];
  const float* bn    = (const float*)d_in[11];

  char* p = (char*)d_ws;
  __hip_bfloat16* W1t   = (__hip_bfloat16*)(p + 0);
  __hip_bfloat16* W2t   = (__hip_bfloat16*)(p + 524288);
  __hip_bfloat16* Wzrt  = (__hip_bfloat16*)(p + 1048576);
  __hip_bfloat16* Wnt   = (__hip_bfloat16*)(p + 3670016);
  float*          hf    = (float*)(p + 6291456);
  float*          hstdf = (float*)(p + 8388608);
  __hip_bfloat16* hbf   = (__hip_bfloat16*)(p + 14680064);
  __hip_bfloat16* Ubf   = (__hip_bfloat16*)(p + 15728640);
  __hip_bfloat16* hodeb = (__hip_bfloat16*)(p + 16777216);
  __hip_bfloat16* hstdb = (__hip_bfloat16*)(p + 17825792);
  __hip_bfloat16* A4    = (__hip_bfloat16*)(p + 18874368);
  __hip_bfloat16* xstep = (__hip_bfloat16*)(p + 20971520);
  unsigned*       bar   = (unsigned*)(p + 21495808);

  hipMemsetAsync(hbf, 0, 1048576, stream);
  hipMemsetAsync(hstdb, 0, 1048576, stream);
  hipMemsetAsync(bar, 0, 8192, stream);

  k_wt<<<(512 * 512 + 255) / 256, 256, 0, stream>>>(W1, W1t, 512, 512, 512);
  k_wt<<<(512 * 512 + 255) / 256, 256, 0, stream>>>(W2, W2t, 512, 512, 512);
  k_wt<<<(1280 * 512 + 255) / 256, 256, 0, stream>>>(Wz, Wzrt, 1280, 512, 1280);
  k_wt<<<(1280 * 512 + 255) / 256, 256, 0, stream>>>(Wr, Wzrt + (size_t)512 * 1280, 1280, 512, 1280);
  k_wt<<<(1280 * 1024 + 255) / 256, 256, 0, stream>>>(Wn, Wnt, 1280, 1024, 1280);

  // persistent kernel: r13 mapping; zero LDS; A via sc0 buffer_load_dwordx4
  // (compiler-pipelined, L1-bypass), B via plain cached loads; free-running
  // unrolled k-loops; 4 strip barriers per step
  k_fused<<<NBLK, NTHR, 0, stream>>>(x, xtime, W1t, b1, W2t, b2, Wzrt, bz, br,
                                     Wnt, bn, hf, hstdf, hbf, Ubf,
                                     hodeb, hstdb, A4, xstep, bar);

  hipMemcpyAsync(d_out, hf, 2097152, hipMemcpyDeviceToDevice, stream);
  hipMemcpyAsync((char*)d_out + 2097152, hstdf, 2097152, hipMemcpyDeviceToDevice, stream);
}